// Round 12
// baseline (2192.052 us; speedup 1.0000x reference)
//
#include <hip/hip_runtime.h>

// Problem constants
#define BB 4
#define SS 32
#define CC 128
#define HH 16
#define WW 32
#define HID 128
#define DEPTH 2
#define CIN 256           // CC + HID
#define COUT 512          // 4*HID
#define K9 (CIN * 9)      // 2304
#define KH 1152           // per-source K: tap-major k = tap*128 + ch
#define KFULL (2 * KH)    // 2304 = x-part rows then h-part rows
#define HW (HH * WW)      // 512
#define MM (BB * HW)      // 2048
#define QS (BB * HID * HW)  // 262144, one step slice (also one packed-x slice)

typedef __attribute__((ext_vector_type(4))) float f32x4;
typedef __attribute__((ext_vector_type(8))) short bf16x8;

static __device__ __forceinline__ unsigned short f2bf(float f) {
    union { float f; unsigned u; } v; v.f = f;
    unsigned r = v.u + 0x7FFF + ((v.u >> 16) & 1);   // RNE
    return (unsigned short)(r >> 16);
}
static __device__ __forceinline__ float bf2f(unsigned short h) {
    union { float f; unsigned u; } v; v.u = ((unsigned)h) << 16; return v.f;
}
static __device__ __forceinline__ unsigned packhl(float f) {
    unsigned short hi = f2bf(f);
    unsigned short lo = f2bf(f - bf2f(hi));
    return (unsigned)hi | ((unsigned)lo << 16);
}

// ---------------------------------------------------------------------------
// Weight transpose: conv_w [DEPTH][COUT][CIN][3][3] -> wcat [DEPTH][COUT_g][KFULL]
// (k-major rows so step-kernel B loads are contiguous uint2 along k)
// k row: cin<CC -> tap*CC+cin (x block), else KH + tap*HID + (cin-CC) (h block).
// n GATE-GATHERED: n' = (r>>4)*64 + g*16 + (r&15), g=n>>7, r=n&127 — a 64-wide
// n-tile holds all 4 gates of one 16-hid slice. Packed bf16 hi|lo.
// ---------------------------------------------------------------------------
__global__ void transpose_w_kernel(const float* __restrict__ w,
                                   unsigned* __restrict__ wcat) {
    int idx = blockIdx.x * 256 + threadIdx.x;
    if (idx >= DEPTH * K9 * COUT) return;
    int n = idx % COUT;
    int k = (idx / COUT) % K9;
    int d = idx / (COUT * K9);
    int cin = k / 9, tap = k % 9;
    float v = w[(((long)(d * COUT + n) * CIN + cin) * 9) + tap];
    int row = (cin < CC) ? (tap * CC + cin) : (KH + tap * HID + (cin - CC));
    int g = n >> 7, r = n & 127;
    int ng = (r >> 4) * 64 + g * 16 + (r & 15);
    wcat[((long)d * COUT + ng) * KFULL + row] = packhl(v);
}

// ---------------------------------------------------------------------------
// Pack x [B][S][CC][HW] fp32 -> xpack [S][B][CC][HW] bf16 hi|lo u32
// ---------------------------------------------------------------------------
__global__ void pack_x_kernel(const float* __restrict__ x, unsigned* __restrict__ xp) {
    int idx = blockIdx.x * 256 + threadIdx.x;     // S*B*CC*HW = 8,388,608
    int hw = idx & 511;
    int cc = (idx >> 9) & 127;
    int sb = idx >> 16;          // s*BB + b
    int b  = sb & 3;
    int s  = sb >> 2;
    float v = x[(((long)(b * SS + s)) * CC + cc) * HW + hw];
    xp[idx] = packhl(v);
}

// ---------------------------------------------------------------------------
// Broadcast init_h/init_c[d] into packed-h / fp32-c state buffers
// ---------------------------------------------------------------------------
__global__ void init_state_kernel(const float* __restrict__ ih, const float* __restrict__ ic,
                                  unsigned* __restrict__ hhl, float* __restrict__ c, int d) {
    int idx = blockIdx.x * 256 + threadIdx.x;   // B*HID*HW = 262144
    int hid = (idx >> 9) & (HID - 1);
    hhl[idx] = packhl(ih[d * HID + hid]);
    c[idx] = ic[d * HID + hid];
}

// ---------------------------------------------------------------------------
// DUAL-LAYER fused step kernel. Flat grid 1024, XCD-stable swizzle:
//   xcd = bid&7, q = bid>>3; mblk = q&63; panel p = xcd + 8*(q>>6);
//   nblk = p&7, layer z = p>>3.
// Each XCD touches exactly 2 weight panels (~1.2 MB) -> L2-resident.
// Layer z runs its step's full conv GEMM (K=2304: 18 x-part + 18 h-part
// BK=64 tiles, tap-major, bf16x3 MFMA) + complete LSTM cell update.
// m-tile 32 (one image row), 4 waves (2m x 2n of 16x32).
// ---------------------------------------------------------------------------
__launch_bounds__(256)
__global__ void step_dual(const unsigned* __restrict__ x1, const unsigned* __restrict__ h1,
                          float* __restrict__ c1, unsigned* __restrict__ ho1,
                          const unsigned* __restrict__ x2, const unsigned* __restrict__ h2,
                          float* __restrict__ c2, unsigned* __restrict__ ho2,
                          const unsigned* __restrict__ w1, const unsigned* __restrict__ w2,
                          const float* __restrict__ bias1, const float* __restrict__ bias2,
                          int do1, int do2) {
    __shared__ __align__(16) union {
        struct {
            unsigned short Ah[2][32][36], Al[2][32][36];   // 9.2 KB
            unsigned short Bh[2][64][36], Bl[2][64][36];   // 18.4 KB
        } s;                                               // 27.6 KB total
        float zt[64][36];   // [n_gathered][m] 9.2 KB
    } u;

    // XCD-stable swizzle
    const int bid  = blockIdx.x;
    const int xcd  = bid & 7;
    const int q    = bid >> 3;          // 0..127
    const int mblk = q & 63;
    const int p    = xcd + ((q >> 6) << 3);   // panel 0..15
    const int nblk = p & 7;
    const int z    = p >> 3;

    if (z == 0) { if (!do1) return; } else { if (!do2) return; }
    const unsigned* xsrc = z ? x2 : x1;
    const unsigned* hsrc = z ? h2 : h1;
    const unsigned* wsel = z ? w2 : w1;
    const float*    bsel = z ? bias2 : bias1;
    float*          csel = z ? c2 : c1;
    unsigned*       hosel = z ? ho2 : ho1;

    const int m0   = mblk * 32;             // one image row
    const int n0g  = nblk * 64;             // gathered-n base
    const int hid0 = nblk * 16;
    const int tid  = threadIdx.x;
    const int lane = tid & 63;
    const int wid  = tid >> 6;
    const int wm = (wid >> 1) * 16;         // m offset within 32
    const int wn = (wid & 1) * 32;          // n offset within 64
    const int b   = m0 >> 9;
    const int hw0 = m0 & 511;
    const int y0  = hw0 >> 5;               // image row

    f32x4 acc[2];
    acc[0] = (f32x4){0.f, 0.f, 0.f, 0.f};
    acc[1] = (f32x4){0.f, 0.f, 0.f, 0.f};

    unsigned pa[8], pb[16];
    auto loadA = [&](int tt) {
        const unsigned* asrc = (tt < 18) ? xsrc : hsrc;
        const int ksub = (tt < 18) ? tt : tt - 18;
        const int k0  = ksub * 64;
        const int tap = k0 >> 7;
        const int c0  = k0 & 127;           // 0 or 64
        const int ky  = tap / 3 - 1;
        const int kx  = tap - (tap / 3) * 3 - 1;
        const int yy  = y0 + ky;
        const bool yok = (unsigned)yy < (unsigned)HH;
        #pragma unroll
        for (int i = 0; i < 4; ++i) {
            int idx = i * 256 + tid;        // 0..1023
            int kkp = idx >> 5;             // ch pair 0..31
            int m   = idx & 31;
            int xq  = m + kx;
            bool ok = yok && (unsigned)xq < (unsigned)WW;
            int ch = c0 + 2 * kkp;
            long base = ((long)(b * 128 + ch)) * HW + yy * WW + xq;
            pa[2 * i]     = ok ? asrc[base] : 0u;
            pa[2 * i + 1] = ok ? asrc[base + HW] : 0u;
        }
    };
    auto loadB = [&](int tt) {
        const int k0 = tt * 64;             // k row base in wcat [COUT][KFULL]
        #pragma unroll
        for (int i = 0; i < 8; ++i) {
            int idx = i * 256 + tid;        // 0..2047
            int kpair = idx & 31;           // k = k0 + 2*kpair
            int n   = idx >> 5;             // 0..63
            uint2 v = *(const uint2*)&wsel[((long)(n0g + n)) * KFULL + k0 + 2 * kpair];
            pb[2 * i]     = v.x;
            pb[2 * i + 1] = v.y;
        }
    };
    auto commit = [&]() {
        #pragma unroll
        for (int i = 0; i < 4; ++i) {
            int idx = i * 256 + tid;
            int kkp = idx >> 5;
            int m   = idx & 31;
            int sub = kkp >> 4;
            int kl  = (2 * kkp) & 31;
            unsigned a0 = pa[2 * i], a1 = pa[2 * i + 1];
            *(unsigned*)&u.s.Ah[sub][m][kl] = (a0 & 0xffffu) | (a1 << 16);
            *(unsigned*)&u.s.Al[sub][m][kl] = (a0 >> 16) | (a1 & 0xffff0000u);
        }
        #pragma unroll
        for (int i = 0; i < 8; ++i) {
            int idx = i * 256 + tid;
            int kpair = idx & 31;
            int n   = idx >> 5;
            int sub = kpair >> 4;
            int kl  = (2 * kpair) & 31;
            unsigned b0 = pb[2 * i], b1 = pb[2 * i + 1];
            *(unsigned*)&u.s.Bh[sub][n][kl] = (b0 & 0xffffu) | (b1 << 16);
            *(unsigned*)&u.s.Bl[sub][n][kl] = (b0 >> 16) | (b1 & 0xffff0000u);
        }
    };

    loadA(0); loadB(0);
    commit();
    __syncthreads();

    const int fr = lane & 15;
    const int kq = (lane >> 4) * 8;

    for (int tt = 0; tt < 36; ++tt) {       // 36 tiles of 64 k
        const bool more = (tt + 1 < 36);
        if (more) { loadA(tt + 1); loadB(tt + 1); }

        #pragma unroll
        for (int sub = 0; sub < 2; ++sub) {
            bf16x8 ah, al, bh[2], bl[2];
            ah = *(const bf16x8*)&u.s.Ah[sub][wm + fr][kq];
            al = *(const bf16x8*)&u.s.Al[sub][wm + fr][kq];
            #pragma unroll
            for (int f = 0; f < 2; ++f) {
                bh[f] = *(const bf16x8*)&u.s.Bh[sub][wn + f * 16 + fr][kq];
                bl[f] = *(const bf16x8*)&u.s.Bl[sub][wn + f * 16 + fr][kq];
            }
            #pragma unroll
            for (int fn = 0; fn < 2; ++fn) {
                acc[fn] = __builtin_amdgcn_mfma_f32_16x16x32_bf16(ah, bh[fn], acc[fn], 0, 0, 0);
                acc[fn] = __builtin_amdgcn_mfma_f32_16x16x32_bf16(ah, bl[fn], acc[fn], 0, 0, 0);
                acc[fn] = __builtin_amdgcn_mfma_f32_16x16x32_bf16(al, bh[fn], acc[fn], 0, 0, 0);
            }
        }
        __syncthreads();
        if (more) {
            commit();
            __syncthreads();
        }
    }

    // --- spill z-tile to LDS (union member switch: all prior reads synced) ---
    {
        const int rm = (lane >> 4) * 4;
        const int cn = lane & 15;
        #pragma unroll
        for (int fn = 0; fn < 2; ++fn) {
            int n = wn + fn * 16 + cn;
            *(float4*)&u.zt[n][wm + rm] = *(float4*)&acc[fn];
        }
    }
    __syncthreads();

    // --- gate math: 512 cell elements (32 m x 16 hid), 2 per thread ---
    #pragma unroll
    for (int i = 0; i < 2; ++i) {
        int e = i * 256 + tid;
        int m = e & 31;
        int j = e >> 5;             // hid slice index 0..15
        float g[4];
        #pragma unroll
        for (int gi = 0; gi < 4; ++gi) {
            int n_orig = gi * 128 + hid0 + j;
            g[gi] = u.zt[gi * 16 + j][m] + bsel[n_orig];
        }
        long idx_s = ((long)(b * HID + hid0 + j)) * HW + hw0 + m;
        float si = 1.f / (1.f + expf(-g[0]));
        float sf = 1.f / (1.f + expf(-g[1]));
        float so = 1.f / (1.f + expf(-g[3]));
        float cs = sf * csel[idx_s] + si * tanhf(g[2]);
        float hs = so * tanhf(cs);
        csel[idx_s] = cs;
        hosel[idx_s] = packhl(hs);
    }
}

// ---------------------------------------------------------------------------
// Mean pool over HW: seq_hl [S][B][HID][HW] packed -> pooled [S*B*HID]
// ---------------------------------------------------------------------------
__global__ void pool_kernel(const unsigned* __restrict__ seq_hl, float* __restrict__ pooled) {
    int row  = blockIdx.x * 4 + (threadIdx.x >> 6);
    int lane = threadIdx.x & 63;
    const unsigned* p = seq_hl + (long)row * HW;
    float sum = 0.f;
    #pragma unroll
    for (int i = 0; i < HW / 64; ++i) {
        unsigned v = p[lane + i * 64];
        sum += bf2f((unsigned short)v) + bf2f((unsigned short)(v >> 16));
    }
    #pragma unroll
    for (int off = 32; off; off >>= 1) sum += __shfl_down(sum, off);
    if (lane == 0) pooled[row] = sum * (1.f / HW);
}

// ---------------------------------------------------------------------------
// FC + ReLU + two scalar heads.
// ---------------------------------------------------------------------------
__global__ void head_kernel(const float* __restrict__ pooled,
                            const float* __restrict__ fc_w, const float* __restrict__ fc_b,
                            const float* __restrict__ fco_w, const float* __restrict__ fco_b,
                            const float* __restrict__ fca_w, const float* __restrict__ fca_b,
                            float* __restrict__ out) {
    int bs = blockIdx.x;          // b*S + s
    int b  = bs / SS;
    int s  = bs % SS;
    int j  = threadIdx.x;
    const float* prow = pooled + (long)(s * BB + b) * HID;
    float acc = fc_b[j];
    #pragma unroll 4
    for (int k = 0; k < HID; ++k) acc += fc_w[j * HID + k] * prow[k];
    float f = fmaxf(acc, 0.f);
    __shared__ float ro[128], ra[128];
    ro[j] = f * fco_w[j];
    ra[j] = f * fca_w[j];
    __syncthreads();
    for (int off = 64; off; off >>= 1) {
        if (j < off) { ro[j] += ro[j + off]; ra[j] += ra[j + off]; }
        __syncthreads();
    }
    if (j == 0) {
        out[bs]           = ro[0] + fco_b[0];
        out[BB * SS + bs] = ra[0] + fca_b[0];
    }
}

// ---------------------------------------------------------------------------
extern "C" void kernel_launch(void* const* d_in, const int* in_sizes, int n_in,
                              void* d_out, int out_size, void* d_ws, size_t ws_size,
                              hipStream_t stream) {
    const float* x      = (const float*)d_in[0];
    const float* conv_w = (const float*)d_in[1];
    const float* conv_b = (const float*)d_in[2];
    const float* init_h = (const float*)d_in[3];
    const float* init_c = (const float*)d_in[4];
    const float* fc_w   = (const float*)d_in[5];
    const float* fc_b   = (const float*)d_in[6];
    const float* fco_w  = (const float*)d_in[7];
    const float* fco_b  = (const float*)d_in[8];
    const float* fca_w  = (const float*)d_in[9];
    const float* fca_b  = (const float*)d_in[10];
    float* out = (float*)d_out;

    // Workspace (4B units), total ~28.6M words = ~114 MB.
    unsigned* wcat  = (unsigned*)d_ws;                   // DEPTH*COUT*KFULL = 2,359,296
    unsigned* xpack = wcat + (long)DEPTH * COUT * KFULL; // S*B*CC*HW = 8,388,608
    unsigned* seq1  = xpack + (long)SS * QS;             // 8,388,608
    unsigned* seq2  = seq1 + (long)SS * QS;              // 8,388,608
    unsigned* hhl1  = seq2 + (long)SS * QS;              // 262,144
    float*    c1    = (float*)(hhl1 + QS);               // 262,144
    unsigned* hhl2  = (unsigned*)((float*)c1 + QS);      // 262,144
    float*    c2    = (float*)(hhl2 + QS);               // 262,144
    float*  pooled  = (float*)((float*)c2 + QS);         // 16,384

    transpose_w_kernel<<<(DEPTH * K9 * COUT + 255) / 256, 256, 0, stream>>>(conv_w, wcat);
    pack_x_kernel<<<(SS * QS) / 256, 256, 0, stream>>>(x, xpack);
    init_state_kernel<<<QS / 256, 256, 0, stream>>>(init_h, init_c, hhl1, c1, 0);
    init_state_kernel<<<QS / 256, 256, 0, stream>>>(init_h, init_c, hhl2, c2, 1);

    const unsigned* w1 = wcat;
    const unsigned* w2 = wcat + (long)COUT * KFULL;

    for (int t = 0; t <= SS; ++t) {
        int do1 = (t < SS) ? 1 : 0;
        int do2 = (t >= 1) ? 1 : 0;
        int t1 = (t < SS) ? t : SS - 1;          // clamped for safe ptr arith
        int u2 = (t >= 1) ? t - 1 : 0;
        const unsigned* x1 = xpack + (long)t1 * QS;
        const unsigned* h1 = (t1 == 0) ? hhl1 : seq1 + (long)(t1 - 1) * QS;
        unsigned* ho1 = seq1 + (long)t1 * QS;
        const unsigned* x2 = seq1 + (long)u2 * QS;
        const unsigned* h2 = (u2 == 0) ? hhl2 : seq2 + (long)(u2 - 1) * QS;
        unsigned* ho2 = seq2 + (long)u2 * QS;
        step_dual<<<dim3(1024), 256, 0, stream>>>(
            x1, h1, c1, ho1, x2, h2, c2, ho2,
            w1, w2, conv_b, conv_b + COUT, do1, do2);
    }

    pool_kernel<<<(SS * BB * HID) / 4, 256, 0, stream>>>(seq2, pooled);
    head_kernel<<<BB * SS, 128, 0, stream>>>(pooled, fc_w, fc_b, fco_w, fco_b, fca_w, fca_b, out);
}

// Round 13
// 1626.996 us; speedup vs baseline: 1.3473x; 1.3473x over previous
//
#include <hip/hip_runtime.h>

// Problem constants
#define BB 4
#define SS 32
#define CC 128
#define HH 16
#define WW 32
#define HID 128
#define DEPTH 2
#define CIN 256           // CC + HID
#define COUT 512          // 4*HID
#define K9 (CIN * 9)      // 2304
#define KH 1152           // per-source K: tap-major k = tap*128 + ch
#define KFULL (2 * KH)    // 2304 = x-part rows then h-part rows
#define HW (HH * WW)      // 512
#define MM (BB * HW)      // 2048
#define ACT (BB * HW * 128) // 262144 = one activation slice (b,hw,ch)

typedef __attribute__((ext_vector_type(4))) float f32x4;
typedef __attribute__((ext_vector_type(8))) short bf16x8;

static __device__ __forceinline__ unsigned short f2bf(float f) {
    union { float f; unsigned u; } v; v.f = f;
    unsigned r = v.u + 0x7FFF + ((v.u >> 16) & 1);   // RNE
    return (unsigned short)(r >> 16);
}
static __device__ __forceinline__ float bf2f(unsigned short h) {
    union { float f; unsigned u; } v; v.u = ((unsigned)h) << 16; return v.f;
}

// ---------------------------------------------------------------------------
// Weight transpose -> separate hi/lo bf16 planes, k-major:
//   wh/wl [DEPTH][COUT_g][KFULL] ushort
// k row: cin<CC -> tap*CC+cin (x block) else KH + tap*HID + (cin-CC) (h block)
// n gate-gathered: n' = (r>>4)*64 + g*16 + (r&15)
// ---------------------------------------------------------------------------
__global__ void transpose_w_kernel(const float* __restrict__ w,
                                   unsigned short* __restrict__ wh,
                                   unsigned short* __restrict__ wl) {
    int idx = blockIdx.x * 256 + threadIdx.x;
    if (idx >= DEPTH * K9 * COUT) return;
    int n = idx % COUT;
    int k = (idx / COUT) % K9;
    int d = idx / (COUT * K9);
    int cin = k / 9, tap = k % 9;
    float v = w[(((long)(d * COUT + n) * CIN + cin) * 9) + tap];
    int row = (cin < CC) ? (tap * CC + cin) : (KH + tap * HID + (cin - CC));
    int g = n >> 7, r = n & 127;
    int ng = (r >> 4) * 64 + g * 16 + (r & 15);
    unsigned short hi = f2bf(v);
    unsigned short lo = f2bf(v - bf2f(hi));
    long o = ((long)d * COUT + ng) * KFULL + row;
    wh[o] = hi;
    wl[o] = lo;
}

// ---------------------------------------------------------------------------
// Pack x [B][S][CC][HW] fp32 -> hi/lo planes [s][b][hw][cc] (ch-contiguous)
// ---------------------------------------------------------------------------
__global__ void pack_x_kernel(const float* __restrict__ x,
                              unsigned short* __restrict__ xh,
                              unsigned short* __restrict__ xl) {
    int idx = blockIdx.x * 256 + threadIdx.x;     // S*ACT = 8,388,608
    int cc = idx & 127;
    int hw = (idx >> 7) & 511;
    int sb = idx >> 16;          // s*BB + b
    int b  = sb & 3;
    int s  = sb >> 2;
    float v = x[(((long)(b * SS + s)) * CC + cc) * HW + hw];
    unsigned short hi = f2bf(v);
    xh[idx] = hi;
    xl[idx] = f2bf(v - bf2f(hi));
}

// ---------------------------------------------------------------------------
// Broadcast init_h/init_c[d] into hi/lo h planes ([b][hw][hid]) + fp32 c
// ---------------------------------------------------------------------------
__global__ void init_state_kernel(const float* __restrict__ ih, const float* __restrict__ ic,
                                  unsigned short* __restrict__ hh, unsigned short* __restrict__ hl,
                                  float* __restrict__ c, int d) {
    int idx = blockIdx.x * 256 + threadIdx.x;   // ACT = 262144
    int hid = idx & 127;
    float v = ih[d * HID + hid];
    unsigned short hi = f2bf(v);
    hh[idx] = hi;
    hl[idx] = f2bf(v - bf2f(hi));
    c[idx] = ic[d * HID + hid];
}

// Zero the 256B OOB page (workspace is poisoned 0xAA before timing)
__global__ void zero_kernel(unsigned* __restrict__ zp) { zp[threadIdx.x] = 0u; }

// ---------------------------------------------------------------------------
// DUAL-LAYER fused step kernel, lean staging:
//  - hi/lo planes pre-split -> staging = 4x uint4 load + 4x ds_write_b128 /wave
//  - XOR-swizzled LDS (chunk ^= row&7 on source index) -> conflict-free b128
//  - single barrier per K-tile (commit-after-compute double buffer)
// M=64 per wg (2 image rows), N=64 (4 gates x 16 hid), BK=64, 512 thr (8 waves
// 4m x 2n, wave tile 16x32). Grid 512 flat, XCD-stable swizzle (2 panels/XCD).
// K = 36 tiles: tt<18 from x-source, tt>=18 from h-source (tap-major).
// ---------------------------------------------------------------------------
__launch_bounds__(512)
__global__ void step_dual(
    const unsigned short* __restrict__ x1h, const unsigned short* __restrict__ x1l,
    const unsigned short* __restrict__ h1h, const unsigned short* __restrict__ h1l,
    float* __restrict__ c1, unsigned short* __restrict__ o1h, unsigned short* __restrict__ o1l,
    const unsigned short* __restrict__ x2h, const unsigned short* __restrict__ x2l,
    const unsigned short* __restrict__ h2h, const unsigned short* __restrict__ h2l,
    float* __restrict__ c2, unsigned short* __restrict__ o2h, unsigned short* __restrict__ o2l,
    const unsigned short* __restrict__ wh, const unsigned short* __restrict__ wl,
    const float* __restrict__ bias, const unsigned short* __restrict__ zp,
    int do1, int do2)
{
    // buf layout (ushort idx): A_hi [0,4096) rows m*64+k, A_lo [4096,8192),
    // B_hi [8192,12288), B_lo [12288,16384). 2 bufs = 64 KB.
    __shared__ __align__(16) unsigned short lds[2][16384];

    // XCD-stable swizzle: xcd = bid&7 -> fixed (nblk, layer) panel
    const int bid  = blockIdx.x;
    const int xcd  = bid & 7;
    const int q    = bid >> 3;               // 0..63
    const int mblk = q & 31;
    const int pp   = xcd + ((q >> 5) << 3);  // panel 0..15
    const int nblk = pp & 7;
    const int z    = pp >> 3;
    if (z == 0) { if (!do1) return; } else { if (!do2) return; }

    const unsigned short* axh = z ? x2h : x1h;
    const unsigned short* axl = z ? x2l : x1l;
    const unsigned short* ahh = z ? h2h : h1h;
    const unsigned short* ahl = z ? h2l : h1l;
    const unsigned short* wph = wh + (long)z * COUT * KFULL;
    const unsigned short* wpl = wl + (long)z * COUT * KFULL;
    const float* bsel  = bias + z * COUT;
    float* csel        = z ? c2 : c1;
    unsigned short* ohh = z ? o2h : o1h;
    unsigned short* ohl = z ? o2l : o1l;

    const int m0   = mblk * 64;
    const int n0g  = nblk * 64;
    const int hid0 = nblk * 16;
    const int tid  = threadIdx.x;
    const int lane = tid & 63;
    const int wv   = tid >> 6;              // wave 0..7
    const int wm   = (wv >> 1) * 16;        // wave m offset (4 m-slices)
    const int wn   = (wv & 1) * 32;         // wave n offset (2 n-slices)
    const int b    = m0 >> 9;
    const int hwl  = m0 & 511;
    const int y0   = hwl >> 5;              // first image row (2 rows per wg)

    // staging geometry: wave stages rows 8*wv..8*wv+7; lane i: row 8wv+(i>>3),
    // chunk j=i&7, source chunk j^(row&7) (the swizzle)
    const int rowoff = wv * 8 + (lane >> 3);    // local row (m or n)
    const int jj     = lane & 7;
    const int jxr    = jj ^ (rowoff & 7);
    const int sx     = rowoff & 31;
    const int sy     = y0 + (rowoff >> 5);
    const long bhw   = (long)b * HW;
    const long boff  = (long)(n0g + rowoff) * KFULL + jxr * 8;   // B row base
    const int  seg   = wv * 512 + lane * 8;      // LDS segment (ushort idx)

    uint4 ra_h, ra_l, rb_h, rb_l;
    auto ld = [&](int tt) {
        const int k0 = tt * 64;
        rb_h = *(const uint4*)(wph + boff + k0);
        rb_l = *(const uint4*)(wpl + boff + k0);
        int ksub = (tt < 18) ? tt : tt - 18;
        int tap  = ksub >> 1;
        int c0   = (ksub & 1) << 6;
        int ky   = tap / 3 - 1;
        int kx   = tap - (tap / 3) * 3 - 1;
        int yy   = sy + ky;
        int xq   = sx + kx;
        bool ok  = (unsigned)yy < (unsigned)HH && (unsigned)xq < (unsigned)WW;
        long aoff = ((bhw + yy * WW + xq) << 7) + c0 + jxr * 8;
        const unsigned short* sh = (tt < 18) ? axh : ahh;
        const unsigned short* sl = (tt < 18) ? axl : ahl;
        ra_h = *(const uint4*)(ok ? sh + aoff : zp);
        ra_l = *(const uint4*)(ok ? sl + aoff : zp);
    };
    auto commit = [&](int pb) {
        *(uint4*)&lds[pb][seg]         = ra_h;
        *(uint4*)&lds[pb][4096 + seg]  = ra_l;
        *(uint4*)&lds[pb][8192 + seg]  = rb_h;
        *(uint4*)&lds[pb][12288 + seg] = rb_l;
    };

    f32x4 acc0 = (f32x4){0.f, 0.f, 0.f, 0.f};
    f32x4 acc1 = (f32x4){0.f, 0.f, 0.f, 0.f};

    const int fr  = lane & 15;
    const int kqi = lane >> 4;              // 0..3 (k chunk within sub)
    const int am  = wm + fr;                // A row
    const int bn0 = wn + fr;                // B rows (2 n-frags)
    const int bn1 = wn + 16 + fr;

    ld(0); commit(0);
    __syncthreads();
    int p = 0;
    for (int tt = 0; tt < 36; ++tt) {
        const bool more = (tt + 1 < 36);
        if (more) ld(tt + 1);               // loads in flight during compute
        const unsigned short* L = &lds[p][0];
        #pragma unroll
        for (int sub = 0; sub < 2; ++sub) {
            const int ca = sub * 4 + kqi;   // chunk 0..7
            bf16x8 ahv = *(const bf16x8*)&L[am * 64 + ((ca ^ (am & 7)) << 3)];
            bf16x8 alv = *(const bf16x8*)&L[4096 + am * 64 + ((ca ^ (am & 7)) << 3)];
            bf16x8 bh0 = *(const bf16x8*)&L[8192 + bn0 * 64 + ((ca ^ (bn0 & 7)) << 3)];
            bf16x8 bl0 = *(const bf16x8*)&L[12288 + bn0 * 64 + ((ca ^ (bn0 & 7)) << 3)];
            bf16x8 bh1 = *(const bf16x8*)&L[8192 + bn1 * 64 + ((ca ^ (bn1 & 7)) << 3)];
            bf16x8 bl1 = *(const bf16x8*)&L[12288 + bn1 * 64 + ((ca ^ (bn1 & 7)) << 3)];
            acc0 = __builtin_amdgcn_mfma_f32_16x16x32_bf16(ahv, bh0, acc0, 0, 0, 0);
            acc0 = __builtin_amdgcn_mfma_f32_16x16x32_bf16(ahv, bl0, acc0, 0, 0, 0);
            acc0 = __builtin_amdgcn_mfma_f32_16x16x32_bf16(alv, bh0, acc0, 0, 0, 0);
            acc1 = __builtin_amdgcn_mfma_f32_16x16x32_bf16(ahv, bh1, acc1, 0, 0, 0);
            acc1 = __builtin_amdgcn_mfma_f32_16x16x32_bf16(ahv, bl1, acc1, 0, 0, 0);
            acc1 = __builtin_amdgcn_mfma_f32_16x16x32_bf16(alv, bh1, acc1, 0, 0, 0);
        }
        if (more) commit(1 - p);            // write NEXT buffer after compute
        __syncthreads();                    // one barrier per tile
        p ^= 1;
    }

    // --- epilogue: z-tile via LDS (reuse buffer 0), then LSTM cell update ---
    float* zt = (float*)&lds[0][0];         // [64 n_gathered][68 m]
    {
        const int rm = (lane >> 4) * 4;
        const int cn = lane & 15;
        *(float4*)&zt[(wn + cn) * 68 + wm + rm]      = *(float4*)&acc0;
        *(float4*)&zt[(wn + 16 + cn) * 68 + wm + rm] = *(float4*)&acc1;
    }
    __syncthreads();

    #pragma unroll
    for (int i2 = 0; i2 < 2; ++i2) {        // 1024 cell elems, 2/thread
        int e  = i2 * 512 + tid;
        int m  = e & 63;
        int jh = e >> 6;                    // hid slice 0..15
        float g[4];
        #pragma unroll
        for (int gi = 0; gi < 4; ++gi)
            g[gi] = zt[(gi * 16 + jh) * 68 + m] + bsel[gi * 128 + hid0 + jh];
        long idx = ((long)b * HW + hwl + m) * 128 + hid0 + jh;
        float si = 1.f / (1.f + expf(-g[0]));
        float sf = 1.f / (1.f + expf(-g[1]));
        float so = 1.f / (1.f + expf(-g[3]));
        float cs = sf * csel[idx] + si * tanhf(g[2]);
        float hs = so * tanhf(cs);
        csel[idx] = cs;
        unsigned short hi = f2bf(hs);
        ohh[idx] = hi;
        ohl[idx] = f2bf(hs - bf2f(hi));
    }
}

// ---------------------------------------------------------------------------
// Mean pool over HW: seq2 planes [s][b][hw][hid] -> pooled [(s*BB+b)*HID + j]
// ---------------------------------------------------------------------------
__global__ void pool_kernel(const unsigned short* __restrict__ s2h,
                            const unsigned short* __restrict__ s2l,
                            float* __restrict__ pooled) {
    int bs = blockIdx.x;            // s*BB + b
    int j  = threadIdx.x;           // 0..127
    const unsigned short* ph = s2h + (long)bs * HW * 128 + j;
    const unsigned short* pl = s2l + (long)bs * HW * 128 + j;
    float sum = 0.f;
    #pragma unroll 8
    for (int hw = 0; hw < HW; ++hw)
        sum += bf2f(ph[hw * 128]) + bf2f(pl[hw * 128]);
    pooled[bs * HID + j] = sum * (1.f / HW);
}

// ---------------------------------------------------------------------------
// FC + ReLU + two scalar heads.
// ---------------------------------------------------------------------------
__global__ void head_kernel(const float* __restrict__ pooled,
                            const float* __restrict__ fc_w, const float* __restrict__ fc_b,
                            const float* __restrict__ fco_w, const float* __restrict__ fco_b,
                            const float* __restrict__ fca_w, const float* __restrict__ fca_b,
                            float* __restrict__ out) {
    int bs = blockIdx.x;          // b*S + s
    int b  = bs / SS;
    int s  = bs % SS;
    int j  = threadIdx.x;
    const float* prow = pooled + (long)(s * BB + b) * HID;
    float acc = fc_b[j];
    #pragma unroll 4
    for (int k = 0; k < HID; ++k) acc += fc_w[j * HID + k] * prow[k];
    float f = fmaxf(acc, 0.f);
    __shared__ float ro[128], ra[128];
    ro[j] = f * fco_w[j];
    ra[j] = f * fca_w[j];
    __syncthreads();
    for (int off = 64; off; off >>= 1) {
        if (j < off) { ro[j] += ro[j + off]; ra[j] += ra[j + off]; }
        __syncthreads();
    }
    if (j == 0) {
        out[bs]           = ro[0] + fco_b[0];
        out[BB * SS + bs] = ra[0] + fca_b[0];
    }
}

// ---------------------------------------------------------------------------
extern "C" void kernel_launch(void* const* d_in, const int* in_sizes, int n_in,
                              void* d_out, int out_size, void* d_ws, size_t ws_size,
                              hipStream_t stream) {
    const float* x      = (const float*)d_in[0];
    const float* conv_w = (const float*)d_in[1];
    const float* conv_b = (const float*)d_in[2];
    const float* init_h = (const float*)d_in[3];
    const float* init_c = (const float*)d_in[4];
    const float* fc_w   = (const float*)d_in[5];
    const float* fc_b   = (const float*)d_in[6];
    const float* fco_w  = (const float*)d_in[7];
    const float* fco_b  = (const float*)d_in[8];
    const float* fca_w  = (const float*)d_in[9];
    const float* fca_b  = (const float*)d_in[10];
    float* out = (float*)d_out;

    // Workspace carve-up (ushort planes first, then fp32) — total ~114 MB.
    unsigned short* wh  = (unsigned short*)d_ws;            // 2,359,296
    unsigned short* wl  = wh  + (long)DEPTH * COUT * KFULL; // 2,359,296
    unsigned short* xph = wl  + (long)DEPTH * COUT * KFULL; // SS*ACT = 8,388,608
    unsigned short* xpl = xph + (long)SS * ACT;
    unsigned short* s1h = xpl + (long)SS * ACT;
    unsigned short* s1l = s1h + (long)SS * ACT;
    unsigned short* s2h = s1l + (long)SS * ACT;
    unsigned short* s2l = s2h + (long)SS * ACT;
    unsigned short* h1h = s2l + (long)SS * ACT;             // ACT each
    unsigned short* h1l = h1h + ACT;
    unsigned short* h2h = h1l + ACT;
    unsigned short* h2l = h2h + ACT;
    float* c1     = (float*)(h2l + ACT);                    // ACT f32
    float* c2     = c1 + ACT;
    float* pooled = c2 + ACT;                               // 16,384
    unsigned short* zp = (unsigned short*)(pooled + SS * BB * HID); // 256 B zeros

    transpose_w_kernel<<<(DEPTH * K9 * COUT + 255) / 256, 256, 0, stream>>>(conv_w, wh, wl);
    pack_x_kernel<<<(SS * (long)ACT) / 256, 256, 0, stream>>>(x, xph, xpl);
    init_state_kernel<<<ACT / 256, 256, 0, stream>>>(init_h, init_c, h1h, h1l, c1, 0);
    init_state_kernel<<<ACT / 256, 256, 0, stream>>>(init_h, init_c, h2h, h2l, c2, 1);
    zero_kernel<<<1, 64, 0, stream>>>((unsigned*)zp);

    for (int t = 0; t <= SS; ++t) {
        int do1 = (t < SS) ? 1 : 0;
        int do2 = (t >= 1) ? 1 : 0;
        int t1 = (t < SS) ? t : SS - 1;          // clamped for safe ptr arith
        int u2 = (t >= 1) ? t - 1 : 0;
        const unsigned short* ax1h = xph + (long)t1 * ACT;
        const unsigned short* ax1l = xpl + (long)t1 * ACT;
        const unsigned short* ah1h = (t1 == 0) ? h1h : s1h + (long)(t1 - 1) * ACT;
        const unsigned short* ah1l = (t1 == 0) ? h1l : s1l + (long)(t1 - 1) * ACT;
        unsigned short* ao1h = s1h + (long)t1 * ACT;
        unsigned short* ao1l = s1l + (long)t1 * ACT;
        const unsigned short* ax2h = s1h + (long)u2 * ACT;
        const unsigned short* ax2l = s1l + (long)u2 * ACT;
        const unsigned short* ah2h = (u2 == 0) ? h2h : s2h + (long)(u2 - 1) * ACT;
        const unsigned short* ah2l = (u2 == 0) ? h2l : s2l + (long)(u2 - 1) * ACT;
        unsigned short* ao2h = s2h + (long)u2 * ACT;
        unsigned short* ao2l = s2l + (long)u2 * ACT;
        step_dual<<<512, 512, 0, stream>>>(
            ax1h, ax1l, ah1h, ah1l, c1, ao1h, ao1l,
            ax2h, ax2l, ah2h, ah2l, c2, ao2h, ao2l,
            wh, wl, conv_b, zp, do1, do2);
    }

    pool_kernel<<<SS * BB, 128, 0, stream>>>(s2h, s2l, pooled);
    head_kernel<<<BB * SS, 128, 0, stream>>>(pooled, fc_w, fc_b, fco_w, fco_b, fca_w, fca_b, out);
}